// Round 1
// baseline (12248.142 us; speedup 1.0000x reference)
//
#include <hip/hip_runtime.h>
#include <math.h>

// Problem constants
constexpr int B_ = 4096;
constexpr int T_ = 20;
constexpr int XD = 256;   // X_DIM
constexpr int ZD = 128;   // Z_DIM
constexpr int HD = 512;   // H_DIM
constexpr int DD = 384;   // X+Z

__device__ __forceinline__ float lrelu_f(float v) { return v > 0.f ? v : 0.2f * v; }
__device__ __forceinline__ float softplus_f(float v) {
    // numerically stable: log1p(exp(-|x|)) + max(x,0)
    return log1pf(expf(-fabsf(v))) + fmaxf(v, 0.f);
}
__device__ __forceinline__ float sigmoid_f(float v) { return 1.f / (1.f + expf(-v)); }

// C[M,N] = ACT( A1[M,K1] @ W1[N,K1]^T + A2[M,K2] @ W2[N,K2]^T + bias1 + bias2 )
// All row-major; both A and W are contiguous along K (NT GEMM).
// M, N multiples of 64; K1, K2 multiples of 16; all row strides multiples of 4.
// ACT: 0 = none, 1 = leaky_relu(0.2), 2 = softplus(leaky_relu(0.2))
// NDST: 1 or 2 destinations (identical values)
template <int ACT, int NDST>
__global__ __launch_bounds__(256) void gemm_nt(
    const float* __restrict__ A1, int lda1, int K1,
    const float* __restrict__ A2, int lda2, int K2,
    const float* __restrict__ W1, int ldw1,
    const float* __restrict__ W2, int ldw2,
    const float* __restrict__ bias1, const float* __restrict__ bias2,
    float* __restrict__ D1, int ldd1,
    float* __restrict__ D2, int ldd2)
{
    __shared__ float As[16][64];  // [k][m]
    __shared__ float Ws[16][64];  // [k][n]

    const int tid = threadIdx.x;
    const int tx = tid & 15;        // n-dim microtile
    const int ty = tid >> 4;        // m-dim microtile
    const int bm = blockIdx.y * 64;
    const int bn = blockIdx.x * 64;
    const int lrow = tid >> 2;          // 0..63: tile row loaded by this thread
    const int lk0 = (tid & 3) * 4;      // k offset (float4)

    float acc[4][4] = {};

    for (int seg = 0; seg < 2; ++seg) {
        const float* Ag = seg ? A2 : A1;
        const float* Wg = seg ? W2 : W1;
        const int K = seg ? K2 : K1;
        const int lda = seg ? lda2 : lda1;
        const int ldw = seg ? ldw2 : ldw1;
        for (int kb = 0; kb < K; kb += 16) {
            float4 av = *reinterpret_cast<const float4*>(Ag + (size_t)(bm + lrow) * lda + kb + lk0);
            float4 wv = *reinterpret_cast<const float4*>(Wg + (size_t)(bn + lrow) * ldw + kb + lk0);
            __syncthreads();
            As[lk0 + 0][lrow] = av.x; As[lk0 + 1][lrow] = av.y;
            As[lk0 + 2][lrow] = av.z; As[lk0 + 3][lrow] = av.w;
            Ws[lk0 + 0][lrow] = wv.x; Ws[lk0 + 1][lrow] = wv.y;
            Ws[lk0 + 2][lrow] = wv.z; Ws[lk0 + 3][lrow] = wv.w;
            __syncthreads();
#pragma unroll
            for (int kk = 0; kk < 16; ++kk) {
                float4 a = *reinterpret_cast<const float4*>(&As[kk][ty * 4]);
                float4 b = *reinterpret_cast<const float4*>(&Ws[kk][tx * 4]);
                float ar[4] = {a.x, a.y, a.z, a.w};
                float br[4] = {b.x, b.y, b.z, b.w};
#pragma unroll
                for (int i = 0; i < 4; ++i)
#pragma unroll
                    for (int j = 0; j < 4; ++j)
                        acc[i][j] = fmaf(ar[i], br[j], acc[i][j]);
            }
        }
    }

    const int nb = bn + tx * 4;
    float bb[4] = {0.f, 0.f, 0.f, 0.f};
    if (bias1) {
#pragma unroll
        for (int j = 0; j < 4; ++j) bb[j] += bias1[nb + j];
    }
    if (bias2) {
#pragma unroll
        for (int j = 0; j < 4; ++j) bb[j] += bias2[nb + j];
    }
#pragma unroll
    for (int i = 0; i < 4; ++i) {
        const int row = bm + ty * 4 + i;
        float v[4];
#pragma unroll
        for (int j = 0; j < 4; ++j) {
            float x = acc[i][j] + bb[j];
            if (ACT == 1) x = lrelu_f(x);
            else if (ACT == 2) x = softplus_f(lrelu_f(x));
            v[j] = x;
        }
        float4 o = make_float4(v[0], v[1], v[2], v[3]);
        *reinterpret_cast<float4*>(D1 + (size_t)row * ldd1 + nb) = o;
        if (NDST == 2)
            *reinterpret_cast<float4*>(D2 + (size_t)row * ldd2 + nb) = o;
    }
}

// LSTM pointwise: gates [B,2048] order i,f,g,o; updates h,c in place;
// writes h_old -> out_hout, h_new -> out_hlo (pointers pre-offset by t*HD, row stride T*HD)
__global__ __launch_bounds__(256) void lstm_point(
    const float* __restrict__ gates,
    float* __restrict__ h, float* __restrict__ c,
    float* __restrict__ out_hout, float* __restrict__ out_hlo)
{
    const int idx = blockIdx.x * 256 + threadIdx.x;   // < B_*HD
    const int b = idx >> 9;
    const int n = idx & 511;
    const float* g = gates + (size_t)b * (4 * HD);
    const float gi = g[n];
    const float gf = g[HD + n];
    const float gg = g[2 * HD + n];
    const float go = g[3 * HD + n];
    const float cc = c[idx];
    const float hold = h[idx];
    const float cn = sigmoid_f(gf) * cc + sigmoid_f(gi) * tanhf(gg);
    const float hn = sigmoid_f(go) * tanhf(cn);
    c[idx] = cn;
    h[idx] = hn;
    const size_t obase = (size_t)b * (T_ * HD) + n;
    out_hout[obase] = hold;
    out_hlo[obase] = hn;
}

__global__ __launch_bounds__(256) void zero_f(float* p, int n)
{
    const int i = blockIdx.x * 256 + threadIdx.x;
    if (i < n) p[i] = 0.f;
}

extern "C" void kernel_launch(void* const* d_in, const int* in_sizes, int n_in,
                              void* d_out, int out_size, void* d_ws, size_t ws_size,
                              hipStream_t stream)
{
    const float* x    = (const float*)d_in[0];
    // d_in[1] = h_in, d_in[2] = z_in  (unused by the forward pass)
    const float* A    = (const float*)d_in[3];
    const float* Wm1  = (const float*)d_in[4];
    const float* bm1  = (const float*)d_in[5];
    const float* Wm2  = (const float*)d_in[6];
    const float* bm2  = (const float*)d_in[7];
    const float* Wv1  = (const float*)d_in[8];
    const float* bv1  = (const float*)d_in[9];
    const float* Wv2  = (const float*)d_in[10];
    const float* bv2  = (const float*)d_in[11];
    const float* Wphi = (const float*)d_in[12];
    const float* bphi = (const float*)d_in[13];
    const float* W_ih = (const float*)d_in[14];
    const float* W_hh = (const float*)d_in[15];
    const float* b_ih = (const float*)d_in[16];
    const float* b_hh = (const float*)d_in[17];

    float* out = (float*)d_out;
    float* out_z    = out;
    float* out_mean = out_z + (size_t)B_ * T_ * ZD;
    float* out_lv   = out_mean + (size_t)B_ * T_ * ZD;
    float* out_hout = out_lv + (size_t)B_ * T_ * ZD;
    float* out_hlo  = out_hout + (size_t)B_ * T_ * HD;

    // workspace layout (floats)
    float* ws = (float*)d_ws;
    float* h     = ws;                         // B*HD
    float* c     = h + (size_t)B_ * HD;        // B*HD
    float* u_m   = c + (size_t)B_ * HD;        // B*HD
    float* u_v   = u_m + (size_t)B_ * HD;      // B*HD
    float* agg   = u_v + (size_t)B_ * HD;      // B*DD
    float* phi   = agg + (size_t)B_ * DD;      // B*2H
    float* gates = phi + (size_t)B_ * 2 * HD;  // B*4H

    const dim3 blk(256);

    // h = c = 0 (contiguous)
    {
        const int n = 2 * B_ * HD;
        zero_f<<<dim3((n + 255) / 256), blk, 0, stream>>>(h, n);
    }

    for (int t = 0; t < T_; ++t) {
        const float* xt = x + (size_t)t * XD;   // row stride T_*XD

        // u_m = lrelu(x_t @ Wm1x^T + h @ Wm1h^T + bm1)      [B, HD]
        gemm_nt<1, 1><<<dim3(HD / 64, B_ / 64), blk, 0, stream>>>(
            xt, T_ * XD, XD, h, HD, HD,
            Wm1, XD + HD, Wm1 + XD, XD + HD,
            bm1, nullptr, u_m, HD, nullptr, 0);

        // u_v = lrelu(x_t @ Wv1x^T + h @ Wv1h^T + bv1)      [B, HD]
        gemm_nt<1, 1><<<dim3(HD / 64, B_ / 64), blk, 0, stream>>>(
            xt, T_ * XD, XD, h, HD, HD,
            Wv1, XD + HD, Wv1 + XD, XD + HD,
            bv1, nullptr, u_v, HD, nullptr, 0);

        // mean = lrelu(u_m @ Wm2^T + bm2) -> out_z[:,t,:], out_mean[:,t,:]
        gemm_nt<1, 2><<<dim3(ZD / 64, B_ / 64), blk, 0, stream>>>(
            u_m, HD, HD, nullptr, 0, 0,
            Wm2, HD, nullptr, 0,
            bm2, nullptr,
            out_z + (size_t)t * ZD, T_ * ZD,
            out_mean + (size_t)t * ZD, T_ * ZD);

        // logvar = lrelu(u_v @ Wv2^T + bv2) -> out_lv[:,t,:]
        gemm_nt<1, 1><<<dim3(ZD / 64, B_ / 64), blk, 0, stream>>>(
            u_v, HD, HD, nullptr, 0, 0,
            Wv2, HD, nullptr, 0,
            bv2, nullptr,
            out_lv + (size_t)t * ZD, T_ * ZD, nullptr, 0);

        // agg = x_t @ Ax^T + mean @ Az^T                    [B, DD]
        gemm_nt<0, 1><<<dim3(DD / 64, B_ / 64), blk, 0, stream>>>(
            xt, T_ * XD, XD, out_mean + (size_t)t * ZD, T_ * ZD, ZD,
            A, DD, A + XD, DD,
            nullptr, nullptr, agg, DD, nullptr, 0);

        // phi = softplus(lrelu(agg @ Wphi^T + bphi))        [B, 2H]
        gemm_nt<2, 1><<<dim3(2 * HD / 64, B_ / 64), blk, 0, stream>>>(
            agg, DD, DD, nullptr, 0, 0,
            Wphi, DD, nullptr, 0,
            bphi, nullptr, phi, 2 * HD, nullptr, 0);

        // gates = phi @ W_ih^T + h @ W_hh^T + b_ih + b_hh   [B, 4H]
        gemm_nt<0, 1><<<dim3(4 * HD / 64, B_ / 64), blk, 0, stream>>>(
            phi, 2 * HD, 2 * HD, h, HD, HD,
            W_ih, 2 * HD, W_hh, HD,
            b_ih, b_hh, gates, 4 * HD, nullptr, 0);

        // LSTM pointwise + output h_old / h_new
        lstm_point<<<dim3(B_ * HD / 256), blk, 0, stream>>>(
            gates, h, c,
            out_hout + (size_t)t * HD, out_hlo + (size_t)t * HD);
    }
}

// Round 2
// 3754.955 us; speedup vs baseline: 3.2619x; 3.2619x over previous
//
#include <hip/hip_runtime.h>
#include <math.h>

// Problem constants
constexpr int B_ = 4096;
constexpr int T_ = 20;
constexpr int XD = 256;   // X_DIM
constexpr int ZD = 128;   // Z_DIM
constexpr int HD = 512;   // H_DIM
constexpr int DD = 384;   // X+Z

using short8 = __attribute__((ext_vector_type(8))) short;
using bf16x8 = __attribute__((ext_vector_type(8))) __bf16;
using f32x4  = __attribute__((ext_vector_type(4))) float;

__device__ __forceinline__ float lrelu_f(float v) { return v > 0.f ? v : 0.2f * v; }
__device__ __forceinline__ float softplus_f(float v) {
    return log1pf(expf(-fabsf(v))) + fmaxf(v, 0.f);
}
__device__ __forceinline__ float sigmoid_f(float v) { return 1.f / (1.f + expf(-v)); }

// float -> bf16 (round to nearest even), finite inputs
__device__ __forceinline__ unsigned short f2b(float f) {
    unsigned u = __builtin_bit_cast(unsigned, f);
    u += 0x7fff + ((u >> 16) & 1);
    return (unsigned short)(u >> 16);
}

__device__ __forceinline__ f32x4 mfma16(short8 a, short8 b, f32x4 c) {
    return __builtin_amdgcn_mfma_f32_16x16x32_bf16(
        __builtin_bit_cast(bf16x8, a), __builtin_bit_cast(bf16x8, b), c, 0, 0, 0);
}

// C[M,N] = ACT( A1[M,K1] @ W1[N,K1]^T + A2[M,K2] @ W2[N,K2]^T + bias1 + bias2 )
// A*, W* are bf16 (as unsigned short), row-major, K-contiguous.
// M,N multiples of 128; K1,K2 multiples of 32; all row strides multiples of 8.
// ACT: 0=none, 1=lrelu(0.2), 2=softplus(lrelu(0.2))
// NF32: number of fp32 destinations (0..2); BF16OUT: also write bf16 dest.
template <int ACT, int NF32, int BF16OUT>
__global__ __launch_bounds__(256) void gemm_bf16(
    const unsigned short* __restrict__ A1, int lda1, int K1,
    const unsigned short* __restrict__ A2, int lda2, int K2,
    const unsigned short* __restrict__ W1, int ldw1,
    const unsigned short* __restrict__ W2, int ldw2,
    const float* __restrict__ bias1, const float* __restrict__ bias2,
    float* __restrict__ D1, int ldd1,
    float* __restrict__ D2, int ldd2,
    unsigned short* __restrict__ DB, int lddb)
{
    __shared__ unsigned short As[128][40];  // padded: 80B rows -> conflict-free-ish
    __shared__ unsigned short Bs[128][40];

    const int tid  = threadIdx.x;
    const int lane = tid & 63;
    const int wave = tid >> 6;          // 4 waves, 2x2
    const int wr = wave >> 1, wc = wave & 1;
    const int bm = blockIdx.y * 128, bn = blockIdx.x * 128;

    const int srow = tid >> 1;          // staging row 0..127
    const int scol = (tid & 1) * 16;    // staging elem offset 0/16

    f32x4 acc[4][4] = {};               // [mi][ni]

    for (int seg = 0; seg < 2; ++seg) {
        const unsigned short* Ag = seg ? A2 : A1;
        const unsigned short* Wg = seg ? W2 : W1;
        const int K   = seg ? K2 : K1;
        const int lda = seg ? lda2 : lda1;
        const int ldw = seg ? ldw2 : ldw1;
        for (int kb = 0; kb < K; kb += 32) {
            const unsigned short* pa = Ag + (size_t)(bm + srow) * lda + kb + scol;
            const unsigned short* pw = Wg + (size_t)(bn + srow) * ldw + kb + scol;
            uint4 a0 = *reinterpret_cast<const uint4*>(pa);
            uint4 a1 = *reinterpret_cast<const uint4*>(pa + 8);
            uint4 w0 = *reinterpret_cast<const uint4*>(pw);
            uint4 w1 = *reinterpret_cast<const uint4*>(pw + 8);
            __syncthreads();
            *reinterpret_cast<uint4*>(&As[srow][scol])     = a0;
            *reinterpret_cast<uint4*>(&As[srow][scol + 8]) = a1;
            *reinterpret_cast<uint4*>(&Bs[srow][scol])     = w0;
            *reinterpret_cast<uint4*>(&Bs[srow][scol + 8]) = w1;
            __syncthreads();

            const int fr = lane & 15;
            const int fg = lane >> 4;
            short8 af[4], bf[4];
#pragma unroll
            for (int mi = 0; mi < 4; ++mi)
                af[mi] = *reinterpret_cast<const short8*>(&As[wr * 64 + mi * 16 + fr][fg * 8]);
#pragma unroll
            for (int ni = 0; ni < 4; ++ni)
                bf[ni] = *reinterpret_cast<const short8*>(&Bs[wc * 64 + ni * 16 + fr][fg * 8]);
#pragma unroll
            for (int mi = 0; mi < 4; ++mi)
#pragma unroll
                for (int ni = 0; ni < 4; ++ni)
                    acc[mi][ni] = mfma16(af[mi], bf[ni], acc[mi][ni]);
        }
    }

    // epilogue: C/D layout col=lane&15, row=(lane>>4)*4+reg  [verified m89/m91]
    const int fr = lane & 15;
    const int rg = lane >> 4;
    float bb[4];
#pragma unroll
    for (int ni = 0; ni < 4; ++ni) {
        const int col = bn + wc * 64 + ni * 16 + fr;
        float b = 0.f;
        if (bias1) b += bias1[col];
        if (bias2) b += bias2[col];
        bb[ni] = b;
    }
#pragma unroll
    for (int mi = 0; mi < 4; ++mi) {
#pragma unroll
        for (int r = 0; r < 4; ++r) {
            const int row = bm + wr * 64 + mi * 16 + rg * 4 + r;
#pragma unroll
            for (int ni = 0; ni < 4; ++ni) {
                const int col = bn + wc * 64 + ni * 16 + fr;
                float v = acc[mi][ni][r] + bb[ni];
                if (ACT == 1) v = lrelu_f(v);
                else if (ACT == 2) v = softplus_f(lrelu_f(v));
                if (NF32 >= 1) D1[(size_t)row * ldd1 + col] = v;
                if (NF32 >= 2) D2[(size_t)row * ldd2 + col] = v;
                if (BF16OUT)   DB[(size_t)row * lddb + col] = f2b(v);
            }
        }
    }
}

// LSTM pointwise: gates [B,4H] order i,f,g,o; h,c in place; h_bf for next GEMMs
__global__ __launch_bounds__(256) void lstm_point(
    const float* __restrict__ gates,
    float* __restrict__ h, float* __restrict__ c,
    unsigned short* __restrict__ hb,
    float* __restrict__ out_hout, float* __restrict__ out_hlo)
{
    const int idx = blockIdx.x * 256 + threadIdx.x;   // < B_*HD
    const int b = idx >> 9;
    const int n = idx & 511;
    const float* g = gates + (size_t)b * (4 * HD);
    const float gi = g[n];
    const float gf = g[HD + n];
    const float gg = g[2 * HD + n];
    const float go = g[3 * HD + n];
    const float cc = c[idx];
    const float hold = h[idx];
    const float cn = sigmoid_f(gf) * cc + sigmoid_f(gi) * tanhf(gg);
    const float hn = sigmoid_f(go) * tanhf(cn);
    c[idx] = cn;
    h[idx] = hn;
    hb[idx] = f2b(hn);
    const size_t obase = (size_t)b * (T_ * HD) + n;
    out_hout[obase] = hold;
    out_hlo[obase] = hn;
}

__global__ __launch_bounds__(256) void zero_hc(
    float* __restrict__ h, float* __restrict__ c, unsigned short* __restrict__ hb)
{
    const int i = blockIdx.x * 256 + threadIdx.x;   // B_*HD
    h[i] = 0.f; c[i] = 0.f; hb[i] = 0;
}

__global__ __launch_bounds__(256) void f32_to_bf16(
    const float* __restrict__ src, unsigned short* __restrict__ dst, int n4)
{
    const int i = blockIdx.x * 256 + threadIdx.x;
    if (i >= n4) return;
    float4 v = reinterpret_cast<const float4*>(src)[i];
    ushort4 o;
    o.x = f2b(v.x); o.y = f2b(v.y); o.z = f2b(v.z); o.w = f2b(v.w);
    reinterpret_cast<ushort4*>(dst)[i] = o;
}

// convert x[:, t, :] (fp32, row stride T*XD) -> xb [B][XD] bf16
__global__ __launch_bounds__(256) void conv_xt(
    const float* __restrict__ x, int t, unsigned short* __restrict__ xb)
{
    const int i = blockIdx.x * 256 + threadIdx.x;   // over B_*XD/4
    const int b = i >> 6;                            // XD/4 = 64 float4 per row
    const int d = i & 63;
    float4 v = reinterpret_cast<const float4*>(x + (size_t)b * (T_ * XD) + (size_t)t * XD)[d];
    ushort4 o;
    o.x = f2b(v.x); o.y = f2b(v.y); o.z = f2b(v.z); o.w = f2b(v.w);
    reinterpret_cast<ushort4*>(xb)[i] = o;
}

extern "C" void kernel_launch(void* const* d_in, const int* in_sizes, int n_in,
                              void* d_out, int out_size, void* d_ws, size_t ws_size,
                              hipStream_t stream)
{
    const float* x    = (const float*)d_in[0];
    const float* A    = (const float*)d_in[3];
    const float* Wm1  = (const float*)d_in[4];
    const float* bm1  = (const float*)d_in[5];
    const float* Wm2  = (const float*)d_in[6];
    const float* bm2  = (const float*)d_in[7];
    const float* Wv1  = (const float*)d_in[8];
    const float* bv1  = (const float*)d_in[9];
    const float* Wv2  = (const float*)d_in[10];
    const float* bv2  = (const float*)d_in[11];
    const float* Wphi = (const float*)d_in[12];
    const float* bphi = (const float*)d_in[13];
    const float* W_ih = (const float*)d_in[14];
    const float* W_hh = (const float*)d_in[15];
    const float* b_ih = (const float*)d_in[16];
    const float* b_hh = (const float*)d_in[17];

    float* out = (float*)d_out;
    float* out_z    = out;
    float* out_mean = out_z + (size_t)B_ * T_ * ZD;
    float* out_lv   = out_mean + (size_t)B_ * T_ * ZD;
    float* out_hout = out_lv + (size_t)B_ * T_ * ZD;
    float* out_hlo  = out_hout + (size_t)B_ * T_ * HD;

    // ---- workspace layout ----
    char* wp = (char*)d_ws;
    auto alloc_f = [&](size_t n) { float* p = (float*)wp; wp += n * sizeof(float); return p; };
    auto alloc_b = [&](size_t n) { unsigned short* p = (unsigned short*)wp; wp += n * sizeof(unsigned short); return p; };

    float* h     = alloc_f((size_t)B_ * HD);
    float* c     = alloc_f((size_t)B_ * HD);
    float* gates = alloc_f((size_t)B_ * 4 * HD);

    unsigned short* hb    = alloc_b((size_t)B_ * HD);
    unsigned short* xb    = alloc_b((size_t)B_ * XD);
    unsigned short* umb   = alloc_b((size_t)B_ * HD);
    unsigned short* uvb   = alloc_b((size_t)B_ * HD);
    unsigned short* meanb = alloc_b((size_t)B_ * ZD);
    unsigned short* aggb  = alloc_b((size_t)B_ * DD);
    unsigned short* phib  = alloc_b((size_t)B_ * 2 * HD);

    unsigned short* Wm1b  = alloc_b((size_t)HD * (XD + HD));
    unsigned short* Wv1b  = alloc_b((size_t)HD * (XD + HD));
    unsigned short* Wm2b  = alloc_b((size_t)ZD * HD);
    unsigned short* Wv2b  = alloc_b((size_t)ZD * HD);
    unsigned short* Wphib = alloc_b((size_t)2 * HD * DD);
    unsigned short* Wihb  = alloc_b((size_t)4 * HD * 2 * HD);
    unsigned short* Whhb  = alloc_b((size_t)4 * HD * HD);
    unsigned short* Ab    = alloc_b((size_t)DD * DD);

    const dim3 blk(256);

    // init h, c, hb
    zero_hc<<<dim3(B_ * HD / 256), blk, 0, stream>>>(h, c, hb);

    // weight conversions (once per call)
    auto conv = [&](const float* s, unsigned short* d, size_t n) {
        f32_to_bf16<<<dim3((unsigned)((n / 4 + 255) / 256)), blk, 0, stream>>>(s, d, (int)(n / 4));
    };
    conv(Wm1,  Wm1b,  (size_t)HD * (XD + HD));
    conv(Wv1,  Wv1b,  (size_t)HD * (XD + HD));
    conv(Wm2,  Wm2b,  (size_t)ZD * HD);
    conv(Wv2,  Wv2b,  (size_t)ZD * HD);
    conv(Wphi, Wphib, (size_t)2 * HD * DD);
    conv(W_ih, Wihb,  (size_t)4 * HD * 2 * HD);
    conv(W_hh, Whhb,  (size_t)4 * HD * HD);
    conv(A,    Ab,    (size_t)DD * DD);

    for (int t = 0; t < T_; ++t) {
        // x_t -> bf16
        conv_xt<<<dim3(B_ * XD / 4 / 256), blk, 0, stream>>>(x, t, xb);

        // u_m = lrelu([x_t, h] @ Wm1^T + bm1)          [B, HD] -> bf16
        gemm_bf16<1, 0, 1><<<dim3(HD / 128, B_ / 128), blk, 0, stream>>>(
            xb, XD, XD, hb, HD, HD,
            Wm1b, XD + HD, Wm1b + XD, XD + HD,
            bm1, nullptr, nullptr, 0, nullptr, 0, umb, HD);

        // u_v = lrelu([x_t, h] @ Wv1^T + bv1)          [B, HD] -> bf16
        gemm_bf16<1, 0, 1><<<dim3(HD / 128, B_ / 128), blk, 0, stream>>>(
            xb, XD, XD, hb, HD, HD,
            Wv1b, XD + HD, Wv1b + XD, XD + HD,
            bv1, nullptr, nullptr, 0, nullptr, 0, uvb, HD);

        // mean = lrelu(u_m @ Wm2^T + bm2) -> out_z, out_mean (f32), meanb (bf16)
        gemm_bf16<1, 2, 1><<<dim3(ZD / 128, B_ / 128), blk, 0, stream>>>(
            umb, HD, HD, nullptr, 0, 0,
            Wm2b, HD, nullptr, 0,
            bm2, nullptr,
            out_z + (size_t)t * ZD, T_ * ZD,
            out_mean + (size_t)t * ZD, T_ * ZD,
            meanb, ZD);

        // logvar = lrelu(u_v @ Wv2^T + bv2) -> out_lv (f32)
        gemm_bf16<1, 1, 0><<<dim3(ZD / 128, B_ / 128), blk, 0, stream>>>(
            uvb, HD, HD, nullptr, 0, 0,
            Wv2b, HD, nullptr, 0,
            bv2, nullptr,
            out_lv + (size_t)t * ZD, T_ * ZD, nullptr, 0, nullptr, 0);

        // agg = [x_t, mean] @ A^T                      [B, DD] -> bf16
        gemm_bf16<0, 0, 1><<<dim3(DD / 128, B_ / 128), blk, 0, stream>>>(
            xb, XD, XD, meanb, ZD, ZD,
            Ab, DD, Ab + XD, DD,
            nullptr, nullptr, nullptr, 0, nullptr, 0, aggb, DD);

        // phi = softplus(lrelu(agg @ Wphi^T + bphi))   [B, 2H] -> bf16
        gemm_bf16<2, 0, 1><<<dim3(2 * HD / 128, B_ / 128), blk, 0, stream>>>(
            aggb, DD, DD, nullptr, 0, 0,
            Wphib, DD, nullptr, 0,
            bphi, nullptr, nullptr, 0, nullptr, 0, phib, 2 * HD);

        // gates = [phi, h] @ [W_ih|W_hh]^T + b_ih + b_hh   [B, 4H] -> f32
        gemm_bf16<0, 1, 0><<<dim3(4 * HD / 128, B_ / 128), blk, 0, stream>>>(
            phib, 2 * HD, 2 * HD, hb, HD, HD,
            Wihb, 2 * HD, Whhb, HD,
            b_ih, b_hh, gates, 4 * HD, nullptr, 0, nullptr, 0);

        // LSTM pointwise
        lstm_point<<<dim3(B_ * HD / 256), blk, 0, stream>>>(
            gates, h, c, hb,
            out_hout + (size_t)t * HD, out_hlo + (size_t)t * HD);
    }
}

// Round 3
// 2757.262 us; speedup vs baseline: 4.4421x; 1.3618x over previous
//
#include <hip/hip_runtime.h>
#include <math.h>

// Problem constants
constexpr int B_ = 4096;
constexpr int T_ = 20;
constexpr int XD = 256;   // X_DIM
constexpr int ZD = 128;   // Z_DIM
constexpr int HD = 512;   // H_DIM
constexpr int DD = 384;   // X+Z

using short8 = __attribute__((ext_vector_type(8))) short;
using bf16x8 = __attribute__((ext_vector_type(8))) __bf16;
using f32x4  = __attribute__((ext_vector_type(4))) float;

__device__ __forceinline__ float lrelu_f(float v) { return v > 0.f ? v : 0.2f * v; }
__device__ __forceinline__ float softplus_f(float v) {
    return log1pf(expf(-fabsf(v))) + fmaxf(v, 0.f);
}
__device__ __forceinline__ float sigmoid_f(float v) { return 1.f / (1.f + expf(-v)); }

// float -> bf16 (round to nearest even), finite inputs
__device__ __forceinline__ unsigned short f2b(float f) {
    unsigned u = __builtin_bit_cast(unsigned, f);
    u += 0x7fff + ((u >> 16) & 1);
    return (unsigned short)(u >> 16);
}

__device__ __forceinline__ f32x4 mfma16(short8 a, short8 b, f32x4 c) {
    return __builtin_amdgcn_mfma_f32_16x16x32_bf16(
        __builtin_bit_cast(bf16x8, a), __builtin_bit_cast(bf16x8, b), c, 0, 0, 0);
}

// async global->LDS, 16 B per lane; lds base must be wave-uniform
__device__ __forceinline__ void load_lds16(const unsigned short* g, unsigned short* l) {
    __builtin_amdgcn_global_load_lds(
        (const __attribute__((address_space(1))) unsigned int*)g,
        (__attribute__((address_space(3))) unsigned int*)l,
        16, 0, 0);
}

// ---------------------------------------------------------------------------
// 128x128-tile bf16 MFMA GEMM core (m97 structure):
//   C[128,128] += A1[128,K1] @ W1[128,K1]^T + A2[128,K2] @ W2[128,K2]^T
// BK=32. LDS linear [128 rows][4 chunks of 8 bf16], staged via global_load_lds
// with chunk swizzle c' = c ^ ((row>>1)&3) applied on the GLOBAL source and on
// the ds_read side (rule #21); fragment ds_read_b128 is then conflict-free.
// K1,K2 multiples of 32 (K2 may be 0); lda/ldw multiples of 8.
// acc[mi][ni][r]: row = bm + wr*64 + mi*16 + (lane>>4)*4 + r,
//                 col = bn + wc*64 + ni*16 + (lane&15)
// ---------------------------------------------------------------------------
__device__ __forceinline__ void gemm_core(
    const unsigned short* A1, int lda1, int K1,
    const unsigned short* A2, int lda2, int K2,
    const unsigned short* W1, int ldw1,
    const unsigned short* W2, int ldw2,
    int bm, int bn,
    unsigned short* As, unsigned short* Bs,
    f32x4 (&acc)[4][4])
{
    const int tid  = threadIdx.x;
    const int lane = tid & 63;
    const int wave = tid >> 6;
    const int wr = wave >> 1, wc = wave & 1;
    const int fr = lane & 15, fg = lane >> 4;
    const int cswz = fg ^ ((fr >> 1) & 3);      // read-side chunk swizzle

    // staging: 512 chunks (16 B) per operand per K-tile, 2 rounds of 256
    const int j0 = tid;
    const int j1 = 256 + tid;
    const int r0 = j0 >> 2, c0 = (j0 & 3) ^ ((r0 >> 1) & 3);
    const int r1 = j1 >> 2, c1 = (j1 & 3) ^ ((r1 >> 1) & 3);
    unsigned short* lA0 = As + wave * 512;           // wave-uniform LDS bases
    unsigned short* lA1 = As + 2048 + wave * 512;
    unsigned short* lB0 = Bs + wave * 512;
    unsigned short* lB1 = Bs + 2048 + wave * 512;

    for (int seg = 0; seg < 2; ++seg) {
        const unsigned short* Ag = seg ? A2 : A1;
        const unsigned short* Wg = seg ? W2 : W1;
        const int K   = seg ? K2 : K1;
        const int lda = seg ? lda2 : lda1;
        const int ldw = seg ? ldw2 : ldw1;
        for (int kb = 0; kb < K; kb += 32) {
            __syncthreads();   // prior tile's ds_reads done before overwrite
            load_lds16(Ag + (size_t)(bm + r0) * lda + kb + c0 * 8, lA0);
            load_lds16(Ag + (size_t)(bm + r1) * lda + kb + c1 * 8, lA1);
            load_lds16(Wg + (size_t)(bn + r0) * ldw + kb + c0 * 8, lB0);
            load_lds16(Wg + (size_t)(bn + r1) * ldw + kb + c1 * 8, lB1);
            asm volatile("s_waitcnt vmcnt(0)" ::: "memory");
            __syncthreads();

            short8 af[4], bf[4];
#pragma unroll
            for (int mi = 0; mi < 4; ++mi) {
                const int row = wr * 64 + mi * 16 + fr;
                af[mi] = *reinterpret_cast<const short8*>(As + row * 32 + cswz * 8);
            }
#pragma unroll
            for (int ni = 0; ni < 4; ++ni) {
                const int row = wc * 64 + ni * 16 + fr;
                bf[ni] = *reinterpret_cast<const short8*>(Bs + row * 32 + cswz * 8);
            }
#pragma unroll
            for (int mi = 0; mi < 4; ++mi)
#pragma unroll
                for (int ni = 0; ni < 4; ++ni)
                    acc[mi][ni] = mfma16(af[mi], bf[ni], acc[mi][ni]);
        }
    }
}

// GEMM + bias + activation -> bf16 output. ACT: 0 none, 1 lrelu, 2 softplus(lrelu)
template <int ACT>
__global__ __launch_bounds__(256) void k_gemm_act(
    const unsigned short* __restrict__ A1, int lda1, int K1,
    const unsigned short* __restrict__ A2, int lda2, int K2,
    const unsigned short* __restrict__ W1, int ldw1,
    const unsigned short* __restrict__ W2, int ldw2,
    const float* __restrict__ bias,
    unsigned short* __restrict__ DB, int lddb)
{
    __shared__ unsigned short As[128 * 32];
    __shared__ unsigned short Bs[128 * 32];
    const int bm = blockIdx.y * 128, bn = blockIdx.x * 128;
    f32x4 acc[4][4] = {};
    gemm_core(A1, lda1, K1, A2, lda2, K2, W1, ldw1, W2, ldw2, bm, bn, As, Bs, acc);

    const int tid = threadIdx.x, lane = tid & 63, wave = tid >> 6;
    const int wr = wave >> 1, wc = wave & 1, fr = lane & 15, rg = lane >> 4;
    float bb[4];
#pragma unroll
    for (int ni = 0; ni < 4; ++ni)
        bb[ni] = bias ? bias[bn + wc * 64 + ni * 16 + fr] : 0.f;
#pragma unroll
    for (int mi = 0; mi < 4; ++mi)
#pragma unroll
        for (int r = 0; r < 4; ++r) {
            const int row = bm + wr * 64 + mi * 16 + rg * 4 + r;
#pragma unroll
            for (int ni = 0; ni < 4; ++ni) {
                float v = acc[mi][ni][r] + bb[ni];
                if (ACT == 1) v = lrelu_f(v);
                else if (ACT == 2) v = softplus_f(lrelu_f(v));
                DB[(size_t)row * lddb + (bn + wc * 64 + ni * 16 + fr)] = f2b(v);
            }
        }
}

// mean/logvar fused via block-diagonal weight [256 x 1024]:
// cols 0-127 = mean (lrelu) -> out_z, out_mean (f32) + meanb (bf16)
// cols 128-255 = logvar (lrelu) -> out_lv (f32)
__global__ __launch_bounds__(256) void k_meanlv(
    const unsigned short* __restrict__ A,
    const unsigned short* __restrict__ W,
    const float* __restrict__ bias,
    float* __restrict__ oz, float* __restrict__ om, float* __restrict__ olv,
    unsigned short* __restrict__ meanb)
{
    __shared__ unsigned short As[128 * 32];
    __shared__ unsigned short Bs[128 * 32];
    const int bm = blockIdx.y * 128, bn = blockIdx.x * 128;   // bn in {0,128}
    f32x4 acc[4][4] = {};
    gemm_core(A, 1024, 1024, A, 1024, 0, W, 1024, W, 1024, bm, bn, As, Bs, acc);

    const int tid = threadIdx.x, lane = tid & 63, wave = tid >> 6;
    const int wr = wave >> 1, wc = wave & 1, fr = lane & 15, rg = lane >> 4;
    float bb[4];
#pragma unroll
    for (int ni = 0; ni < 4; ++ni)
        bb[ni] = bias[bn + wc * 64 + ni * 16 + fr];
#pragma unroll
    for (int mi = 0; mi < 4; ++mi)
#pragma unroll
        for (int r = 0; r < 4; ++r) {
            const int row = bm + wr * 64 + mi * 16 + rg * 4 + r;
#pragma unroll
            for (int ni = 0; ni < 4; ++ni) {
                const int col = bn + wc * 64 + ni * 16 + fr;
                float v = lrelu_f(acc[mi][ni][r] + bb[ni]);
                if (bn == 0) {  // mean half
                    const size_t o = (size_t)row * (T_ * ZD) + col;
                    oz[o] = v; om[o] = v;
                    meanb[(size_t)row * ZD + col] = f2b(v);
                } else {        // logvar half
                    olv[(size_t)row * (T_ * ZD) + (col - 128)] = v;
                }
            }
        }
}

// gates GEMM with gate-interleaved weight rows + fused LSTM pointwise.
// Reordered col c <-> (group=c>>6, gate=(c>>4)&3, nn=c&15), unit n=group*16+nn.
// Each thread holds all 4 gates of unit n for its 16 rows.
__global__ __launch_bounds__(256) void k_gates_lstm(
    const unsigned short* __restrict__ phib,
    const unsigned short* __restrict__ hbin,
    const unsigned short* __restrict__ Wih,   // [2048][1024] reordered rows
    const unsigned short* __restrict__ Whh,   // [2048][512] reordered rows
    const float* __restrict__ br,             // reordered b_ih+b_hh
    float* __restrict__ h, float* __restrict__ c,
    unsigned short* __restrict__ hbout,
    float* __restrict__ oh, float* __restrict__ ohl)
{
    __shared__ unsigned short As[128 * 32];
    __shared__ unsigned short Bs[128 * 32];
    const int bm = blockIdx.y * 128, bn = blockIdx.x * 128;
    f32x4 acc[4][4] = {};
    gemm_core(phib, 1024, 1024, hbin, 512, 512, Wih, 1024, Whh, 512, bm, bn, As, Bs, acc);

    const int tid = threadIdx.x, lane = tid & 63, wave = tid >> 6;
    const int wr = wave >> 1, wc = wave & 1, fr = lane & 15, rg = lane >> 4;
    const int n = ((bn + wc * 64) >> 6) * 16 + fr;     // hidden unit index
    float bb[4];
#pragma unroll
    for (int ni = 0; ni < 4; ++ni)
        bb[ni] = br[bn + wc * 64 + ni * 16 + fr];
#pragma unroll
    for (int mi = 0; mi < 4; ++mi)
#pragma unroll
        for (int r = 0; r < 4; ++r) {
            const int row = bm + wr * 64 + mi * 16 + rg * 4 + r;
            const size_t idx = (size_t)row * HD + n;
            const float gi = acc[mi][0][r] + bb[0];
            const float gf = acc[mi][1][r] + bb[1];
            const float gg = acc[mi][2][r] + bb[2];
            const float go = acc[mi][3][r] + bb[3];
            const float co = c[idx];
            const float ho = h[idx];
            const float cn = sigmoid_f(gf) * co + sigmoid_f(gi) * tanhf(gg);
            const float hn = sigmoid_f(go) * tanhf(cn);
            c[idx] = cn;
            h[idx] = hn;
            hbout[idx] = f2b(hn);
            const size_t ob = (size_t)row * (T_ * HD) + n;
            oh[ob] = ho;    // h BEFORE update
            ohl[ob] = hn;   // h after update
        }
}

// ---------------------------------------------------------------------------
__global__ __launch_bounds__(256) void zero_hc(
    float* __restrict__ h, float* __restrict__ c, unsigned short* __restrict__ hb)
{
    const int i = blockIdx.x * 256 + threadIdx.x;   // B_*HD
    h[i] = 0.f; c[i] = 0.f; hb[i] = 0;
}

__global__ __launch_bounds__(256) void f32_to_bf16(
    const float* __restrict__ src, unsigned short* __restrict__ dst, int n4)
{
    const int i = blockIdx.x * 256 + threadIdx.x;
    if (i >= n4) return;
    float4 v = reinterpret_cast<const float4*>(src)[i];
    ushort4 o;
    o.x = f2b(v.x); o.y = f2b(v.y); o.z = f2b(v.z); o.w = f2b(v.w);
    reinterpret_cast<ushort4*>(dst)[i] = o;
}

// x[:, t, :] (fp32, row stride T*XD) -> xb [B][XD] bf16
__global__ __launch_bounds__(256) void conv_xt(
    const float* __restrict__ x, int t, unsigned short* __restrict__ xb)
{
    const int i = blockIdx.x * 256 + threadIdx.x;   // B_*XD/4
    const int b = i >> 6;
    const int d = i & 63;
    float4 v = reinterpret_cast<const float4*>(x + (size_t)b * (T_ * XD) + (size_t)t * XD)[d];
    ushort4 o;
    o.x = f2b(v.x); o.y = f2b(v.y); o.z = f2b(v.z); o.w = f2b(v.w);
    reinterpret_cast<ushort4*>(xb)[i] = o;
}

// Wub[1024][768] = [Wm1; Wv1] (bf16)
__global__ __launch_bounds__(256) void prep_wu(
    const float* __restrict__ Wm1, const float* __restrict__ Wv1,
    unsigned short* __restrict__ Wub)
{
    const int k = blockIdx.x * 256 + threadIdx.x;   // 0..767
    const int nrow = blockIdx.y;                    // 0..1023
    const float v = nrow < 512 ? Wm1[nrow * 768 + k] : Wv1[(nrow - 512) * 768 + k];
    Wub[nrow * 768 + k] = f2b(v);
}

// Wmlv[256][1024] block-diagonal: [Wm2 0; 0 Wv2] (bf16)
__global__ __launch_bounds__(256) void prep_wmlv(
    const float* __restrict__ Wm2, const float* __restrict__ Wv2,
    unsigned short* __restrict__ Wmlv)
{
    const int k = blockIdx.x * 256 + threadIdx.x;   // 0..1023
    const int cc = blockIdx.y;                      // 0..255
    float v = 0.f;
    if (cc < 128) { if (k < 512) v = Wm2[cc * 512 + k]; }
    else          { if (k >= 512) v = Wv2[(cc - 128) * 512 + (k - 512)]; }
    Wmlv[cc * 1024 + k] = f2b(v);
}

// gate-interleaved reorder of W_ih, W_hh
__global__ __launch_bounds__(256) void prep_wg(
    const float* __restrict__ Wih, const float* __restrict__ Whh,
    unsigned short* __restrict__ Wrih, unsigned short* __restrict__ Wrhh)
{
    const int cc = blockIdx.y;                      // 0..2047
    const int gate = (cc >> 4) & 3;
    const int n = ((cc >> 6) << 4) + (cc & 15);
    const int orig = gate * 512 + n;
    const int kk = blockIdx.x * 256 + threadIdx.x;  // 0..1535
    if (kk < 1024) Wrih[(size_t)cc * 1024 + kk] = f2b(Wih[(size_t)orig * 1024 + kk]);
    else           Wrhh[(size_t)cc * 512 + (kk - 1024)] = f2b(Whh[(size_t)orig * 512 + (kk - 1024)]);
}

__global__ __launch_bounds__(256) void prep_bias(
    const float* __restrict__ bm1, const float* __restrict__ bv1,
    const float* __restrict__ bm2, const float* __restrict__ bv2,
    const float* __restrict__ bih, const float* __restrict__ bhh,
    float* __restrict__ bu, float* __restrict__ bmlv, float* __restrict__ br)
{
    const int i = blockIdx.x * 256 + threadIdx.x;   // 0..4095
    if (i < 1024) {
        bu[i] = i < 512 ? bm1[i] : bv1[i - 512];
    } else if (i < 1280) {
        const int j = i - 1024;
        bmlv[j] = j < 128 ? bm2[j] : bv2[j - 128];
    } else if (i >= 2048) {
        const int cb = i - 2048;
        const int gate = (cb >> 4) & 3;
        const int n = ((cb >> 6) << 4) + (cb & 15);
        const int orig = gate * 512 + n;
        br[cb] = bih[orig] + bhh[orig];
    }
}

extern "C" void kernel_launch(void* const* d_in, const int* in_sizes, int n_in,
                              void* d_out, int out_size, void* d_ws, size_t ws_size,
                              hipStream_t stream)
{
    const float* x    = (const float*)d_in[0];
    const float* A    = (const float*)d_in[3];
    const float* Wm1  = (const float*)d_in[4];
    const float* bm1  = (const float*)d_in[5];
    const float* Wm2  = (const float*)d_in[6];
    const float* bm2  = (const float*)d_in[7];
    const float* Wv1  = (const float*)d_in[8];
    const float* bv1  = (const float*)d_in[9];
    const float* Wv2  = (const float*)d_in[10];
    const float* bv2  = (const float*)d_in[11];
    const float* Wphi = (const float*)d_in[12];
    const float* bphi = (const float*)d_in[13];
    const float* W_ih = (const float*)d_in[14];
    const float* W_hh = (const float*)d_in[15];
    const float* b_ih = (const float*)d_in[16];
    const float* b_hh = (const float*)d_in[17];

    float* out = (float*)d_out;
    float* out_z    = out;
    float* out_mean = out_z + (size_t)B_ * T_ * ZD;
    float* out_lv   = out_mean + (size_t)B_ * T_ * ZD;
    float* out_hout = out_lv + (size_t)B_ * T_ * ZD;
    float* out_hlo  = out_hout + (size_t)B_ * T_ * HD;

    // ---- workspace layout (~51 MB) ----
    char* wp = (char*)d_ws;
    auto alloc_f = [&](size_t n) { float* p = (float*)wp; wp += n * sizeof(float); return p; };
    auto alloc_b = [&](size_t n) { unsigned short* p = (unsigned short*)wp; wp += n * sizeof(unsigned short); return p; };

    float* h  = alloc_f((size_t)B_ * HD);
    float* c  = alloc_f((size_t)B_ * HD);
    unsigned short* hb0   = alloc_b((size_t)B_ * HD);
    unsigned short* hb1   = alloc_b((size_t)B_ * HD);
    unsigned short* xb    = alloc_b((size_t)B_ * XD);
    unsigned short* umuvb = alloc_b((size_t)B_ * 1024);
    unsigned short* meanb = alloc_b((size_t)B_ * ZD);
    unsigned short* aggb  = alloc_b((size_t)B_ * DD);
    unsigned short* phib  = alloc_b((size_t)B_ * 1024);

    unsigned short* Wub   = alloc_b((size_t)1024 * 768);
    unsigned short* Wmlvb = alloc_b((size_t)256 * 1024);
    unsigned short* Ab    = alloc_b((size_t)DD * DD);
    unsigned short* Wphib = alloc_b((size_t)1024 * DD);
    unsigned short* Wrih  = alloc_b((size_t)2048 * 1024);
    unsigned short* Wrhh  = alloc_b((size_t)2048 * 512);

    float* bu   = alloc_f(1024);
    float* bmlv = alloc_f(256);
    float* br   = alloc_f(2048);

    const dim3 blk(256);

    // ---- prep (once per call) ----
    zero_hc<<<dim3(B_ * HD / 256), blk, 0, stream>>>(h, c, hb0);
    prep_wu<<<dim3(3, 1024), blk, 0, stream>>>(Wm1, Wv1, Wub);
    prep_wmlv<<<dim3(4, 256), blk, 0, stream>>>(Wm2, Wv2, Wmlvb);
    prep_wg<<<dim3(6, 2048), blk, 0, stream>>>(W_ih, W_hh, Wrih, Wrhh);
    prep_bias<<<dim3(16), blk, 0, stream>>>(bm1, bv1, bm2, bv2, b_ih, b_hh, bu, bmlv, br);
    f32_to_bf16<<<dim3(DD * DD / 4 / 256), blk, 0, stream>>>(A, Ab, DD * DD / 4);
    f32_to_bf16<<<dim3(1024 * DD / 4 / 256), blk, 0, stream>>>(Wphi, Wphib, 1024 * DD / 4);

    for (int t = 0; t < T_; ++t) {
        unsigned short* hbt = (t & 1) ? hb1 : hb0;   // h_t  (read)
        unsigned short* hbn = (t & 1) ? hb0 : hb1;   // h_{t+1} (written by epilogue)

        conv_xt<<<dim3(B_ * XD / 4 / 256), blk, 0, stream>>>(x, t, xb);

        // [u_m | u_v] = lrelu([x_t, h] @ Wub^T + bu)   [B, 1024]
        k_gemm_act<1><<<dim3(8, 32), blk, 0, stream>>>(
            xb, XD, XD, hbt, HD, HD,
            Wub, XD + HD, Wub + XD, XD + HD,
            bu, umuvb, 1024);

        // mean -> out_z/out_mean/meanb ; logvar -> out_lv
        k_meanlv<<<dim3(2, 32), blk, 0, stream>>>(
            umuvb, Wmlvb, bmlv,
            out_z + (size_t)t * ZD, out_mean + (size_t)t * ZD,
            out_lv + (size_t)t * ZD, meanb);

        // agg = [x_t, mean] @ A^T   [B, 384]
        k_gemm_act<0><<<dim3(3, 32), blk, 0, stream>>>(
            xb, XD, XD, meanb, ZD, ZD,
            Ab, DD, Ab + XD, DD,
            nullptr, aggb, DD);

        // phi = softplus(lrelu(agg @ Wphi^T + bphi))   [B, 1024]
        k_gemm_act<2><<<dim3(8, 32), blk, 0, stream>>>(
            aggb, DD, DD, aggb, DD, 0,
            Wphib, DD, Wphib, DD,
            bphi, phib, 1024);

        // gates (reordered) + fused LSTM
        k_gates_lstm<<<dim3(16, 32), blk, 0, stream>>>(
            phib, hbt, Wrih, Wrhh, br,
            h, c, hbn,
            out_hout + (size_t)t * HD, out_hlo + (size_t)t * HD);
    }
}